// Round 12
// baseline (512.754 us; speedup 1.0000x reference)
//
#include <hip/hip_runtime.h>

#define Bq 2
#define Hh 8
#define Ss 512
#define HD 64
#define DIM 512

using f32x4   = __attribute__((ext_vector_type(4))) float;
using bf16x8s = __attribute__((ext_vector_type(8))) short;
typedef _Float16 f16x8 __attribute__((ext_vector_type(8)));

__device__ __forceinline__ float bf2f(unsigned short u) {
    return __uint_as_float(((unsigned int)u) << 16);
}
__device__ __forceinline__ unsigned short f2bf(float f) {
    unsigned int u = __float_as_uint(f);
    u = (u + 0x7FFFu + ((u >> 16) & 1u)) >> 16;   // RNE
    return (unsigned short)u;
}

// ============ mm_k: C = A @ B^T + bias (fp32 io, split bf16x2 MFMA, 128x128) ============
__global__ __launch_bounds__(256) void mm_k(
    const float* __restrict__ A, const float* __restrict__ B,
    const float* __restrict__ bias, float* __restrict__ C,
    int K, int ldc)
{
    const int row0 = blockIdx.y * 128, col0 = blockIdx.x * 128;
    __shared__ unsigned short AsH[128][40], AsL[128][40];
    __shared__ unsigned short BsH[128][40], BsL[128][40];
    const int t = threadIdx.x;
    const int wave = t >> 6, lane = t & 63;
    const int ln = lane & 15, quad = lane >> 4;
    const int wm = (wave & 1) * 64, wn = (wave >> 1) * 64;

    f32x4 acc[4][4];
#pragma unroll
    for (int i = 0; i < 4; ++i)
#pragma unroll
        for (int j = 0; j < 4; ++j)
            acc[i][j] = (f32x4){0.f, 0.f, 0.f, 0.f};

    const int sr = t >> 2, sg = (t & 3) * 8;

    for (int k0 = 0; k0 < K; k0 += 32) {
        __syncthreads();
#pragma unroll
        for (int half = 0; half < 4; ++half) {
            const float* src = (half < 2) ? A : B;
            int base = (half < 2) ? row0 : col0;
            int row = sr + ((half & 1) ? 64 : 0);
            const float* p = &src[(long)(base + row) * K + k0 + sg];
            float4 f0 = *(const float4*)p;
            float4 f1 = *(const float4*)(p + 4);
            float fv[8] = {f0.x, f0.y, f0.z, f0.w, f1.x, f1.y, f1.z, f1.w};
            unsigned short hv[8], lv[8];
#pragma unroll
            for (int e = 0; e < 8; ++e) {
                hv[e] = f2bf(fv[e]);
                lv[e] = f2bf(fv[e] - bf2f(hv[e]));
            }
            uint4 H, L;
            H.x = hv[0] | (hv[1] << 16); H.y = hv[2] | (hv[3] << 16);
            H.z = hv[4] | (hv[5] << 16); H.w = hv[6] | (hv[7] << 16);
            L.x = lv[0] | (lv[1] << 16); L.y = lv[2] | (lv[3] << 16);
            L.z = lv[4] | (lv[5] << 16); L.w = lv[6] | (lv[7] << 16);
            if (half < 2) { *(uint4*)&AsH[row][sg] = H; *(uint4*)&AsL[row][sg] = L; }
            else          { *(uint4*)&BsH[row][sg] = H; *(uint4*)&BsL[row][sg] = L; }
        }
        __syncthreads();

        bf16x8s afH[4], afL[4], bfH[4], bfL[4];
#pragma unroll
        for (int mt = 0; mt < 4; ++mt) {
            afH[mt] = *(const bf16x8s*)&AsH[wm + mt * 16 + ln][quad * 8];
            afL[mt] = *(const bf16x8s*)&AsL[wm + mt * 16 + ln][quad * 8];
        }
#pragma unroll
        for (int nt = 0; nt < 4; ++nt) {
            bfH[nt] = *(const bf16x8s*)&BsH[wn + nt * 16 + ln][quad * 8];
            bfL[nt] = *(const bf16x8s*)&BsL[wn + nt * 16 + ln][quad * 8];
        }
#pragma unroll
        for (int mt = 0; mt < 4; ++mt)
#pragma unroll
            for (int nt = 0; nt < 4; ++nt) {
                acc[mt][nt] = __builtin_amdgcn_mfma_f32_16x16x32_bf16(afH[mt], bfH[nt], acc[mt][nt], 0, 0, 0);
                acc[mt][nt] = __builtin_amdgcn_mfma_f32_16x16x32_bf16(afH[mt], bfL[nt], acc[mt][nt], 0, 0, 0);
                acc[mt][nt] = __builtin_amdgcn_mfma_f32_16x16x32_bf16(afL[mt], bfH[nt], acc[mt][nt], 0, 0, 0);
            }
    }

#pragma unroll
    for (int mt = 0; mt < 4; ++mt) {
        const int gr0 = row0 + wm + mt * 16 + quad * 4;
#pragma unroll
        for (int nt = 0; nt < 4; ++nt) {
            const int gc = col0 + wn + nt * 16 + ln;
            float bb = bias[gc];
#pragma unroll
            for (int r = 0; r < 4; ++r)
                C[(long)(gr0 + r) * ldc + gc] = acc[mt][nt][r] + bb;
        }
    }
}

// ============ wt_fused: 64x64 tiles, W fp16 (both layouts) + partials + vT ============
__global__ __launch_bounds__(256) void wt_fused(const float* __restrict__ qkv,
                                                _Float16* __restrict__ Wh,
                                                _Float16* __restrict__ Wt,
                                                _Float16* __restrict__ vT,
                                                float* __restrict__ rsum,
                                                float* __restrict__ rsq,
                                                float* __restrict__ csum)
{
    __shared__ float qs[32][64];
    __shared__ float ks[32][64];
    __shared__ float colacc[64];
    int z = blockIdx.y;
    int b = z >> 3, h = z & 7;
    int t = threadIdx.x;
    int bx = blockIdx.x;
    long zo = (long)z * Ss * Ss;

    if (bx >= 64) {            // vT pack: half dh (d 32-chunk), all k
        float (*sT)[33] = (float(*)[33])qs;
        int dt = (bx - 64) * 32;
        int d = t & 31, kr = t >> 5;
        for (int kt = 0; kt < Ss; kt += 32) {
            __syncthreads();
#pragma unroll
            for (int p = 0; p < 4; ++p) {
                int kk = kr + p * 8;
                sT[kk][d] = qkv[(long)b * (Ss * 3 * DIM) + (long)(kt + kk) * (3 * DIM) + 2 * DIM + h * HD + dt + d];
            }
            __syncthreads();
#pragma unroll
            for (int p = 0; p < 4; ++p) {
                int dd = kr + p * 8;
                vT[(long)z * (HD * Ss) + (long)(dt + dd) * Ss + kt + d] = (_Float16)sT[d][dd];
            }
        }
        return;
    }

    int ti = bx >> 3, tj = bx & 7;
    int i0 = ti * 64, j0 = tj * 64;

    if (tj > ti) {             // fully-masked: zero both layouts + partial slots
        uint4 zz = make_uint4(0, 0, 0, 0);
        int row = t >> 2, c16 = (t & 3) * 16;
        *(uint4*)&Wt[zo + (long)(j0 + row) * Ss + i0 + c16]     = zz;
        *(uint4*)&Wt[zo + (long)(j0 + row) * Ss + i0 + c16 + 8] = zz;
        *(uint4*)&Wh[zo + (long)(i0 + row) * Ss + j0 + c16]     = zz;
        *(uint4*)&Wh[zo + (long)(i0 + row) * Ss + j0 + c16 + 8] = zz;
        if (t < 64) {
            rsum[((z * 8 + ti) * 512) + j0 + t] = 0.f;
            rsq [((z * 8 + ti) * 512) + j0 + t] = 0.f;
            csum[((z * 8 + tj) * 512) + i0 + t] = 0.f;
        }
        return;
    }

    int ia = (t & 15) * 4;
    int ja = (t >> 4) * 4;
    const float* qb = qkv + (long)b * Ss * (3 * DIM) + h * HD;
    const float* kb = qb + DIM;
    float acc[4][4] = {};

    for (int d0 = 0; d0 < 64; d0 += 32) {
        __syncthreads();
        int row = t & 63, dg = (t >> 6) * 8;
        float4 qv  = *(const float4*)&qb[(long)(i0 + row) * (3 * DIM) + d0 + dg];
        float4 qv2 = *(const float4*)&qb[(long)(i0 + row) * (3 * DIM) + d0 + dg + 4];
        float4 kv  = *(const float4*)&kb[(long)(j0 + row) * (3 * DIM) + d0 + dg];
        float4 kv2 = *(const float4*)&kb[(long)(j0 + row) * (3 * DIM) + d0 + dg + 4];
        qs[dg+0][row] = qv.x;  qs[dg+1][row] = qv.y;  qs[dg+2][row] = qv.z;  qs[dg+3][row] = qv.w;
        qs[dg+4][row] = qv2.x; qs[dg+5][row] = qv2.y; qs[dg+6][row] = qv2.z; qs[dg+7][row] = qv2.w;
        ks[dg+0][row] = kv.x;  ks[dg+1][row] = kv.y;  ks[dg+2][row] = kv.z;  ks[dg+3][row] = kv.w;
        ks[dg+4][row] = kv2.x; ks[dg+5][row] = kv2.y; ks[dg+6][row] = kv2.z; ks[dg+7][row] = kv2.w;
        __syncthreads();
#pragma unroll
        for (int d = 0; d < 32; ++d) {
            float4 q0 = *(const float4*)&qs[d][ia];
            float4 k0 = *(const float4*)&ks[d][ja];
            float qv_[4] = {q0.x, q0.y, q0.z, q0.w};
            float kv_[4] = {k0.x, k0.y, k0.z, k0.w};
#pragma unroll
            for (int aa = 0; aa < 4; ++aa)
#pragma unroll
                for (int c = 0; c < 4; ++c)
                    acc[aa][c] += fabsf(qv_[aa] - kv_[c]);
        }
    }

#pragma unroll
    for (int aa = 0; aa < 4; ++aa) {
        int i = i0 + ia + aa;
#pragma unroll
        for (int c = 0; c < 4; ++c) {
            int j = j0 + ja + c;
            float e = expf(-acc[aa][c] * 0.25f);
            acc[aa][c] = (j <= i) ? e : 0.0f;
        }
    }
#pragma unroll
    for (int c = 0; c < 4; ++c) {
        int j = j0 + ja + c;
        float rs = 0.f, rq = 0.f;
#pragma unroll
        for (int aa = 0; aa < 4; ++aa) { rs += acc[aa][c]; rq += acc[aa][c] * acc[aa][c]; }
        _Float16 ha[4] __attribute__((aligned(8))) = {(_Float16)acc[0][c], (_Float16)acc[1][c], (_Float16)acc[2][c], (_Float16)acc[3][c]};
        *(uint2*)&Wt[zo + (long)j * Ss + i0 + ia] = *(const uint2*)ha;
#pragma unroll
        for (int off = 8; off > 0; off >>= 1) {
            rs += __shfl_down(rs, off, 16);
            rq += __shfl_down(rq, off, 16);
        }
        if ((t & 15) == 0) {
            rsum[((z * 8 + ti) * 512) + j] = rs;
            rsq [((z * 8 + ti) * 512) + j] = rq;
        }
    }
#pragma unroll
    for (int aa = 0; aa < 4; ++aa) {
        int i = i0 + ia + aa;
        _Float16 hb[4] __attribute__((aligned(8))) = {(_Float16)acc[aa][0], (_Float16)acc[aa][1], (_Float16)acc[aa][2], (_Float16)acc[aa][3]};
        *(uint2*)&Wh[zo + (long)i * Ss + j0 + ja] = *(const uint2*)hb;
    }
    __syncthreads();
    if (t < 64) colacc[t] = 0.f;
    __syncthreads();
#pragma unroll
    for (int aa = 0; aa < 4; ++aa) {
        float cs = acc[aa][0] + acc[aa][1] + acc[aa][2] + acc[aa][3];
        atomicAdd(&colacc[ia + aa], cs);
    }
    __syncthreads();
    if (t < 64) csum[((z * 8 + tj) * 512) + i0 + t] = colacc[t];
}

// ============ fin_k: scal[z] (blocks 0..15); mu/inv_sig per h (blocks 16..23) ============
__global__ __launch_bounds__(256) void fin_k(const float* __restrict__ rsum,
                                             const float* __restrict__ rsq,
                                             const float* __restrict__ csum,
                                             float* __restrict__ scal,
                                             float* __restrict__ mu,
                                             float* __restrict__ inv_sig)
{
    __shared__ float s1[256], s2[256];
    int bx = blockIdx.x, t = threadIdx.x;
    if (bx < 16) {
        int z = bx;
        float mx1 = 0.f, mx2 = 0.f;
        for (int jj = t; jj < 512; jj += 256) {
            float rs = 0.f, cs = 0.f;
#pragma unroll
            for (int ti = 0; ti < 8; ++ti) {
                rs += rsum[(z * 8 + ti) * 512 + jj];
                cs += csum[(z * 8 + ti) * 512 + jj];
            }
            mx1 = fmaxf(mx1, rs);
            mx2 = fmaxf(mx2, cs);
        }
        s1[t] = mx1; s2[t] = mx2;
        __syncthreads();
        for (int off = 128; off > 0; off >>= 1) {
            if (t < off) {
                s1[t] = fmaxf(s1[t], s1[t + off]);
                s2[t] = fmaxf(s2[t], s2[t + off]);
            }
            __syncthreads();
        }
        if (t == 0) scal[z] = 1.0f / (s1[0] * s2[0]);
    } else {
        int h = bx - 16;
        for (int jj = t; jj < 512; jj += 256) {
            float s = 0.f, q = 0.f;
#pragma unroll
            for (int b = 0; b < 2; ++b)
#pragma unroll
                for (int ti = 0; ti < 8; ++ti) {
                    int zz = b * 8 + h;
                    s += rsum[(zz * 8 + ti) * 512 + jj];
                    q += rsq [(zz * 8 + ti) * 512 + jj];
                }
            float m_ = s / 1024.f;
            float var = (q - s * s / 1024.f) / 1023.f;
            inv_sig[h * 512 + jj] = 1.0f / sqrtf(var + 1e-5f);
            mu[h * 512 + jj] = m_;
        }
    }
}

// ============ fg_k<MODE>: symmetric fp16 GEMM, 64x64 lower tiles + mirror (36x16 blocks) ============
// MODE 0: T0 = -s * A@A^T (kend=col0+64).  MODE 1: T' = 2*V + A@A^T (full K).
template<int MODE>
__global__ __launch_bounds__(256) void fg_k(const _Float16* __restrict__ A,
                                            const _Float16* V,
                                            _Float16* __restrict__ R,
                                            const float* __restrict__ scal)
{
    const int tIs[36] = {0,1,1,2,2,2,3,3,3,3,4,4,4,4,4,5,5,5,5,5,5,6,6,6,6,6,6,6,7,7,7,7,7,7,7,7};
    const int tJs[36] = {0,0,1,0,1,2,0,1,2,3,0,1,2,3,4,0,1,2,3,4,5,0,1,2,3,4,5,6,0,1,2,3,4,5,6,7};
    __shared__ _Float16 As[64][40];
    __shared__ _Float16 Bs[64][40];
    const int z = blockIdx.y;
    const long zo = (long)z * Ss * Ss;
    const int ti = tIs[blockIdx.x], tj = tJs[blockIdx.x];
    const int row0 = ti * 64, col0 = tj * 64;
    const bool diag = (ti == tj);
    const int kend = (MODE == 0) ? (col0 + 64) : Ss;
    const int t = threadIdx.x;
    const int wave = t >> 6, lane = t & 63;
    const int ln = lane & 15, quad = lane >> 4;
    const int r4 = t >> 2, c4 = (t & 3) * 8;

    f32x4 acc[4];
#pragma unroll
    for (int i = 0; i < 4; ++i) acc[i] = (f32x4){0.f, 0.f, 0.f, 0.f};

    const long aoff = zo + (long)(row0 + r4) * Ss;
    const long boff = zo + (long)(col0 + r4) * Ss;
    uint4 ua = *(const uint4*)&A[aoff + c4];
    uint4 ub = *(const uint4*)&A[boff + c4];

    for (int k0 = 0; k0 < kend; k0 += 32) {
        *(uint4*)&As[r4][c4] = ua;
        *(uint4*)&Bs[r4][c4] = ub;
        __syncthreads();
        int kn = k0 + 32;
        if (kn < kend) {
            ua = *(const uint4*)&A[aoff + kn + c4];
            ub = *(const uint4*)&A[boff + kn + c4];
        }
        f16x8 af = *(const f16x8*)&As[wave * 16 + ln][quad * 8];
#pragma unroll
        for (int nt = 0; nt < 4; ++nt) {
            f16x8 bf = *(const f16x8*)&Bs[nt * 16 + ln][quad * 8];
            acc[nt] = __builtin_amdgcn_mfma_f32_16x16x32_f16(af, bf, acc[nt], 0, 0, 0);
        }
        __syncthreads();
    }

    float s = (MODE == 0) ? scal[z] : 0.f;
    const int gr0 = row0 + wave * 16 + quad * 4;
#pragma unroll
    for (int nt = 0; nt < 4; ++nt) {
        const int gc = col0 + nt * 16 + ln;
        _Float16 rb[4] __attribute__((aligned(8)));
#pragma unroll
        for (int r = 0; r < 4; ++r) {
            const long gi = zo + (long)(gr0 + r) * Ss + gc;
            float val;
            if (MODE == 0) val = -s * acc[nt][r];
            else           val = 2.0f * (float)V[gi] + acc[nt][r];
            _Float16 o = (_Float16)val;
            R[gi] = o;
            rb[r] = o;
        }
        if (!diag)
            *(uint2*)&R[zo + (long)gc * Ss + gr0] = *(const uint2*)rb;
    }
}

// ============ mega_y: per-block (z, 16-row d-slice) persistent y chain ============
// Stages: 0: y0 = vT x Wt (tri=1). 1-5: y = 2y + y x T_k (k=4..0). 6: c2s = iss*s*(y x Wt)
// (tri=1) + negoff. 7: gat = Wh @ c2s - neg (tri=2), written [B,S,DIM].
// Grid 64 = 16 z x 4 d-slices. y slice lives in LDS the whole time.
__global__ __launch_bounds__(256) void mega_y(const _Float16* __restrict__ vT,
                                              const _Float16* __restrict__ Wt,
                                              const _Float16* __restrict__ Wh,
                                              const _Float16* __restrict__ Tb,
                                              const float* __restrict__ scal,
                                              const float* __restrict__ mu,
                                              const float* __restrict__ inv_sig,
                                              float* __restrict__ gat)
{
    __shared__ _Float16 yA[16][520];     // 16,640 B  (row stride 1040 B, 16B-aligned)
    __shared__ _Float16 Bst[512][40];    // 40,960 B
    __shared__ float mus[512];           // 2,048 B
    __shared__ float iss[512];           // 2,048 B
    __shared__ float negs[16];           // 64 B       total ~61.8 KB
    const int z = blockIdx.x >> 2, ds = blockIdx.x & 3;
    const int b = z >> 3, h = z & 7;
    const int t = threadIdx.x;
    const int wave = t >> 6, lane = t & 63;
    const int ln = lane & 15, quad = lane >> 4;
    const long zW = (long)z * Ss * Ss;
    const long zV = (long)z * (HD * Ss) + (long)(ds * 16) * Ss;

    // init: mus/iss, negs, vT slice -> yA
    for (int j = t; j < 512; j += 256) {
        mus[j] = mu[h * 512 + j];
        iss[j] = inv_sig[h * 512 + j];
    }
    if (t < 16) negs[t] = 0.f;
    {
        int d = t >> 4, cg = (t & 15) * 32;
        *(uint4*)&yA[d][cg]      = *(const uint4*)&vT[zV + (long)d * Ss + cg];
        *(uint4*)&yA[d][cg + 8]  = *(const uint4*)&vT[zV + (long)d * Ss + cg + 8];
        *(uint4*)&yA[d][cg + 16] = *(const uint4*)&vT[zV + (long)d * Ss + cg + 16];
        *(uint4*)&yA[d][cg + 24] = *(const uint4*)&vT[zV + (long)d * Ss + cg + 24];
    }
    const float sc = scal[z];
    const int dd = quad * 4;             // d-base for this lane's outputs

    for (int st = 0; st < 8; ++st) {
        const _Float16* Bmat;
        int tri;
        if (st == 0)      { Bmat = Wt + zW; tri = 1; }
        else if (st <= 5) { Bmat = Tb + (long)(5 - st) * 4194304 + zW; tri = 0; }
        else if (st == 6) { Bmat = Wt + zW; tri = 1; }
        else              { Bmat = Wh + zW; tri = 2; }

        f32x4 acc[2][4];
#pragma unroll
        for (int i = 0; i < 2; ++i)
#pragma unroll
            for (int j = 0; j < 4; ++j)
                acc[i][j] = (f32x4){0.f, 0.f, 0.f, 0.f};

        uint4 pb[8];
#pragma unroll
        for (int i = 0; i < 8; ++i) {
            int u = t + 256 * i;
            pb[i] = *(const uint4*)&Bmat[(long)(u >> 2) * Ss + (u & 3) * 8];
        }

        for (int kt = 0; kt < 16; ++kt) {
            const int k0 = kt * 32;
#pragma unroll
            for (int i = 0; i < 8; ++i) {
                int u = t + 256 * i;
                *(uint4*)&Bst[u >> 2][(u & 3) * 8] = pb[i];
            }
            if (kt < 15) {
#pragma unroll
                for (int i = 0; i < 8; ++i) {
                    int u = t + 256 * i;
                    pb[i] = *(const uint4*)&Bmat[(long)(u >> 2) * Ss + k0 + 32 + (u & 3) * 8];
                }
            }
            __syncthreads();
            f16x8 af = *(const f16x8*)&yA[ln][k0 + quad * 8];
#pragma unroll
            for (int cl = 0; cl < 2; ++cl) {
                int c = wave * 2 + cl;
                if (tri == 1 && c * 64 > k0 + 31) continue;
                if (tri == 2 && k0 > c * 64 + 63) continue;
#pragma unroll
                for (int nt = 0; nt < 4; ++nt) {
                    f16x8 bf = *(const f16x8*)&Bst[c * 64 + nt * 16 + ln][quad * 8];
                    acc[cl][nt] = __builtin_amdgcn_mfma_f32_16x16x32_f16(af, bf, acc[cl][nt], 0, 0, 0);
                }
            }
            __syncthreads();
        }

        // ---- epilogue ----
        if (st == 0) {
#pragma unroll
            for (int cl = 0; cl < 2; ++cl)
#pragma unroll
                for (int nt = 0; nt < 4; ++nt) {
                    int n = (wave * 2 + cl) * 64 + nt * 16 + ln;
#pragma unroll
                    for (int r = 0; r < 4; ++r)
                        yA[dd + r][n] = (_Float16)acc[cl][nt][r];
                }
        } else if (st <= 5) {
#pragma unroll
            for (int cl = 0; cl < 2; ++cl)
#pragma unroll
                for (int nt = 0; nt < 4; ++nt) {
                    int n = (wave * 2 + cl) * 64 + nt * 16 + ln;
#pragma unroll
                    for (int r = 0; r < 4; ++r) {
                        float val = 2.0f * (float)yA[dd + r][n] + acc[cl][nt][r];
                        yA[dd + r][n] = (_Float16)val;
                    }
                }
        } else if (st == 6) {
            float pr[4] = {0.f, 0.f, 0.f, 0.f};
#pragma unroll
            for (int cl = 0; cl < 2; ++cl)
#pragma unroll
                for (int nt = 0; nt < 4; ++nt) {
                    int n = (wave * 2 + cl) * 64 + nt * 16 + ln;
#pragma unroll
                    for (int r = 0; r < 4; ++r) {
                        float val = iss[n] * (sc * acc[cl][nt][r]);
                        pr[r] += mus[n] * val;
                        yA[dd + r][n] = (_Float16)val;
                    }
                }
#pragma unroll
            for (int r = 0; r < 4; ++r) {
#pragma unroll
                for (int off = 8; off > 0; off >>= 1)
                    pr[r] += __shfl_down(pr[r], off, 16);
            }
            if (ln == 0) {
#pragma unroll
                for (int r = 0; r < 4; ++r)
                    atomicAdd(&negs[dd + r], pr[r]);
            }
        } else {
            float (*fbuf)[20] = (float(*)[20])&Bst[0][0];
            for (int c = 0; c < 8; ++c) {
                __syncthreads();
                if (wave == (c >> 1)) {
                    int cl = c & 1;
#pragma unroll
                    for (int nt = 0; nt < 4; ++nt) {
#pragma unroll
                        for (int r = 0; r < 4; ++r)
                            fbuf[nt * 16 + ln][dd + r] = acc[cl][nt][r] - negs[dd + r];
                    }
                }
                __syncthreads();
                int ml = t >> 2, dg = (t & 3) * 4;
                long base = (long)b * (Ss * DIM) + (long)(c * 64 + ml) * DIM + h * 64 + ds * 16 + dg;
                *(float4*)&gat[base] = *(const float4*)&fbuf[ml][dg];
            }
        }
        __syncthreads();
    }
}

extern "C" void kernel_launch(void* const* d_in, const int* in_sizes, int n_in,
                              void* d_out, int out_size, void* d_ws, size_t ws_size,
                              hipStream_t stream)
{
    const float* x      = (const float*)d_in[0];
    const float* qkv_w  = (const float*)d_in[1];
    const float* qkv_b  = (const float*)d_in[2];
    const float* proj_w = (const float*)d_in[3];
    const float* proj_b = (const float*)d_in[4];
    float* out = (float*)d_out;
    float* ws  = (float*)d_ws;

    float* qkv     = ws;
    _Float16* Wh   = (_Float16*)(ws + 1572864);
    _Float16* Wt   = (_Float16*)(ws + 3670016);
    _Float16* vT   = (_Float16*)(ws + 5767168);
    _Float16* Tb   = (_Float16*)(ws + 6029312);     // 5 buffers x 4,194,304 halves
    float* rsum    = ws + 16515072;   // 65536
    float* rsq     = ws + 16580608;   // 65536
    float* csum    = ws + 16646144;   // 65536
    float* scal    = ws + 16711680;   // 16
    float* mu      = ws + 16711696;   // 4096
    float* inv_sig = ws + 16715792;   // 4096
    float* gat     = ws + 16719888;   // 524288

    dim3 blk(256);

    // 1. qkv = x @ qkv_w^T + qkv_b
    mm_k<<<dim3(12, 8), blk, 0, stream>>>(x, qkv_w, qkv_b, qkv, DIM, 3 * DIM);

    // 2. W fp16 (both layouts, 64-tiles) + reduction partials + vT
    wt_fused<<<dim3(66, 16), blk, 0, stream>>>(qkv, Wh, Wt, vT, rsum, rsq, csum);

    // 3. scale + whitening stats
    fin_k<<<dim3(24), blk, 0, stream>>>(rsum, rsq, csum, scal, mu, inv_sig);

    // 4. T0 = -s * W W^T  (symmetric, 36 lower 64-tiles + mirror)
    fg_k<0><<<dim3(36, 16), blk, 0, stream>>>(Wh, nullptr, Tb, scal);

    // 5-8. residual squarings: T' = 2T + T^2
    for (int i = 0; i < 4; ++i)
        fg_k<1><<<dim3(36, 16), blk, 0, stream>>>(Tb + (long)i * 4194304, Tb + (long)i * 4194304,
                                                  Tb + (long)(i + 1) * 4194304, nullptr);

    // 9. mega: y0 + y-chain(5) + c2s(+negoff) + ga  — all per-(z, d-slice) in one block
    mega_y<<<dim3(64), blk, 0, stream>>>(vT, Wt, Wh, Tb, scal, mu, inv_sig, gat);

    // 10. out = gat @ proj_w^T + proj_b
    mm_k<<<dim3(4, 8), blk, 0, stream>>>(gat, proj_w, proj_b, out, DIM, DIM);
}